// Round 2
// baseline (1963.771 us; speedup 1.0000x reference)
//
#include <hip/hip_runtime.h>
#include <math.h>

#define NCODES 16384
#define DIM    256
#define CH     256
#define HW     1024
#define MTOT   16384
#define OUT_ELEMS 4194304

#define BM 64
#define BN 256
#define BK 8

// separately-rounded f32 multiply (blocks FMA contraction: numpy computes
// the product array first, then pairwise-sums it)
__device__ __forceinline__ float mulr(float a, float b) {
    float p = a * b;
    asm volatile("" : "+v"(p));
    return p;
}

// ---------------- kernel 1: codebook row norms, numpy pairwise order ----------------
// np pairwise_sum(256) = pw(128) + pw(128); pw(128): 8 accumulators mod 8,
// combined ((r0+r1)+(r2+r3)) + ((r4+r5)+(r6+r7)). All ops f32-rounded.
__global__ __launch_bounds__(256) void k_cnorm(const float* __restrict__ cb,
                                               float* __restrict__ cnorm) {
    int row = blockIdx.x * 256 + threadIdx.x;
    const float* cp = cb + (size_t)row * DIM;
    float r0[8], r1[8];
    #pragma unroll
    for (int j = 0; j < 8; ++j) {
        float v0 = cp[j], v1 = cp[128 + j];
        r0[j] = mulr(v0, v0);
        r1[j] = mulr(v1, v1);
    }
    for (int i = 8; i < 128; i += 8) {
        #pragma unroll
        for (int j = 0; j < 8; ++j) {
            float v0 = cp[i + j], v1 = cp[128 + i + j];
            r0[j] += mulr(v0, v0);
            r1[j] += mulr(v1, v1);
        }
    }
    float s0 = ((r0[0] + r0[1]) + (r0[2] + r0[3])) + ((r0[4] + r0[5]) + (r0[6] + r0[7]));
    float s1 = ((r1[0] + r1[1]) + (r1[2] + r1[3])) + ((r1[4] + r1[5]) + (r1[6] + r1[7]));
    cnorm[row] = s0 + s1;
}

// ---------------- kernel 1b: z row norms (strided layout), same numpy order ----------
__global__ __launch_bounds__(256) void k_anorm(const float* __restrict__ z,
                                               float* __restrict__ anorm) {
    int m = blockIdx.x * 256 + threadIdx.x;
    int b = m / HW, hw = m % HW;
    const float* zp = z + (size_t)b * (CH * HW) + hw;
    float r0[8], r1[8];
    #pragma unroll
    for (int j = 0; j < 8; ++j) {
        float v0 = zp[(size_t)j * HW];
        float v1 = zp[(size_t)(128 + j) * HW];
        r0[j] = mulr(v0, v0);
        r1[j] = mulr(v1, v1);
    }
    for (int i = 8; i < 128; i += 8) {
        #pragma unroll
        for (int j = 0; j < 8; ++j) {
            float v0 = zp[(size_t)(i + j) * HW];
            float v1 = zp[(size_t)(128 + i + j) * HW];
            r0[j] += mulr(v0, v0);
            r1[j] += mulr(v1, v1);
        }
    }
    float s0 = ((r0[0] + r0[1]) + (r0[2] + r0[3])) + ((r0[4] + r0[5]) + (r0[6] + r0[7]));
    float s1 = ((r1[0] + r1[1]) + (r1[2] + r1[3])) + ((r1[4] + r1[5]) + (r1[6] + r1[7]));
    anorm[m] = s0 + s1;
}

// ---------------- kernel 2: GEMM (sequential-k f32 FMA, BLAS order) + argmin --------
// d(m,n) = fl( fl(A_m + B_n) - 2*P_mn ), argmin with tie -> lowest n
__global__ __launch_bounds__(256) void k_argmin(const float* __restrict__ z,
                                                const float* __restrict__ cb,
                                                const float* __restrict__ cnorm,
                                                const float* __restrict__ anorm,
                                                int* __restrict__ idxi,
                                                float* __restrict__ idxf) {
    __shared__ float lds_a[DIM][BM];     // 64 KB, [d][m]
    __shared__ float lds_b[2][BK][BN];   // 16 KB, [buf][d][n]

    const int t  = threadIdx.x;
    const int tx = t & 15;
    const int ty = t >> 4;
    const int mb = blockIdx.x * BM;
    const int zb = mb / HW;
    const int hw0 = mb % HW;
    const float* zbase = z + (size_t)zb * (CH * HW) + hw0;

    // A tile load (coalesced along hw)
    {
        const int m4 = (t & 15) * 4;
        const int db = t >> 4;
        #pragma unroll
        for (int i = 0; i < 16; ++i) {
            int d = i * 16 + db;
            float4 v = *reinterpret_cast<const float4*>(zbase + (size_t)d * HW + m4);
            *reinterpret_cast<float4*>(&lds_a[d][m4]) = v;
        }
    }

    float Am[4];
    #pragma unroll
    for (int i = 0; i < 4; ++i) Am[i] = anorm[mb + ty * 4 + i];

    float bv[4];
    int   bi[4];
    #pragma unroll
    for (int i = 0; i < 4; ++i) { bv[i] = INFINITY; bi[i] = 0x7fffffff; }

    __syncthreads();

    for (int nt = 0; nt < NCODES / BN; ++nt) {
        const int n0 = nt * BN;

        float cnv[16];
        #pragma unroll
        for (int jb = 0; jb < 4; ++jb) {
            float4 c4 = *reinterpret_cast<const float4*>(cnorm + n0 + jb * 64 + tx * 4);
            cnv[jb * 4 + 0] = c4.x; cnv[jb * 4 + 1] = c4.y;
            cnv[jb * 4 + 2] = c4.z; cnv[jb * 4 + 3] = c4.w;
        }

        float acc[4][16];
        #pragma unroll
        for (int i = 0; i < 4; ++i)
            #pragma unroll
            for (int j = 0; j < 16; ++j) acc[i][j] = 0.f;

        const float* crow = cb + (size_t)(n0 + t) * DIM;

        float4 u0 = *reinterpret_cast<const float4*>(crow + 0);
        float4 u1 = *reinterpret_cast<const float4*>(crow + 4);
        __syncthreads();
        lds_b[0][0][t] = u0.x; lds_b[0][1][t] = u0.y; lds_b[0][2][t] = u0.z; lds_b[0][3][t] = u0.w;
        lds_b[0][4][t] = u1.x; lds_b[0][5][t] = u1.y; lds_b[0][6][t] = u1.z; lds_b[0][7][t] = u1.w;

        for (int kc = 0; kc < DIM / BK; ++kc) {
            const int cur = kc & 1;
            __syncthreads();

            float4 nu0, nu1;
            if (kc < DIM / BK - 1) {
                nu0 = *reinterpret_cast<const float4*>(crow + (kc + 1) * BK);
                nu1 = *reinterpret_cast<const float4*>(crow + (kc + 1) * BK + 4);
            }

            #pragma unroll
            for (int kk = 0; kk < BK; ++kk) {
                const int d = kc * BK + kk;
                float4 av = *reinterpret_cast<const float4*>(&lds_a[d][ty * 4]);
                float bvv[16];
                *reinterpret_cast<float4*>(&bvv[0])  = *reinterpret_cast<const float4*>(&lds_b[cur][kk][tx * 4]);
                *reinterpret_cast<float4*>(&bvv[4])  = *reinterpret_cast<const float4*>(&lds_b[cur][kk][64 + tx * 4]);
                *reinterpret_cast<float4*>(&bvv[8])  = *reinterpret_cast<const float4*>(&lds_b[cur][kk][128 + tx * 4]);
                *reinterpret_cast<float4*>(&bvv[12]) = *reinterpret_cast<const float4*>(&lds_b[cur][kk][192 + tx * 4]);
                const float af[4] = {av.x, av.y, av.z, av.w};
                #pragma unroll
                for (int i = 0; i < 4; ++i)
                    #pragma unroll
                    for (int j = 0; j < 16; ++j)
                        acc[i][j] = fmaf(af[i], bvv[j], acc[i][j]);  // sequential k, FMA: matches sgemm
            }

            if (kc < DIM / BK - 1) {
                const int nb = cur ^ 1;
                lds_b[nb][0][t] = nu0.x; lds_b[nb][1][t] = nu0.y; lds_b[nb][2][t] = nu0.z; lds_b[nb][3][t] = nu0.w;
                lds_b[nb][4][t] = nu1.x; lds_b[nb][5][t] = nu1.y; lds_b[nb][6][t] = nu1.z; lds_b[nb][7][t] = nu1.w;
            }
        }

        // d = fl(fl(Am+Bn) - 2*P); lexicographic (d, n) argmin == np.argmin
        #pragma unroll
        for (int i = 0; i < 4; ++i)
            #pragma unroll
            for (int jb = 0; jb < 4; ++jb)
                #pragma unroll
                for (int jj = 0; jj < 4; ++jj) {
                    float t1 = Am[i] + cnv[jb * 4 + jj];       // f32 round
                    float dd = t1 - 2.0f * acc[i][jb * 4 + jj]; // 2*P exact; sub rounds (fma-contraction equivalent)
                    int n = n0 + jb * 64 + tx * 4 + jj;
                    if (dd < bv[i] || (dd == bv[i] && n < bi[i])) { bv[i] = dd; bi[i] = n; }
                }
    }

    #pragma unroll
    for (int i = 0; i < 4; ++i) {
        #pragma unroll
        for (int o = 1; o < 16; o <<= 1) {
            float ov = __shfl_xor(bv[i], o, 64);
            int   oi = __shfl_xor(bi[i], o, 64);
            if (ov < bv[i] || (ov == bv[i] && oi < bi[i])) { bv[i] = ov; bi[i] = oi; }
        }
        if (tx == 0) {
            int row = mb + ty * 4 + i;
            idxi[row] = bi[i];
            idxf[row] = (float)bi[i];
        }
    }
}

// ---------------- kernel 3: gather z_q, write out, accumulate loss ----------------
__global__ __launch_bounds__(256) void k_gather(const float* __restrict__ z,
                                                const float* __restrict__ cb,
                                                const int* __restrict__ idx,
                                                float* __restrict__ out,
                                                double* __restrict__ lacc) {
    int t = threadIdx.x;
    int hwi = t & 63, cg = t >> 6;
    int m = blockIdx.x * 64 + hwi;
    int b = m / HW, hw = m % HW;
    const float* erow = cb + (size_t)idx[m] * DIM;
    size_t zoff = (size_t)b * (CH * HW) + hw;
    double ls = 0.0;
    #pragma unroll 4
    for (int cc = 0; cc < 64; ++cc) {
        int c = cg * 64 + cc;
        float e  = erow[c];
        float zv = z[zoff + (size_t)c * HW];
        out[zoff + (size_t)c * HW] = e;
        float d = e - zv;
        ls += (double)d * (double)d;
    }
    #pragma unroll
    for (int o = 32; o; o >>= 1) ls += __shfl_xor(ls, o, 64);
    __shared__ double wsum[4];
    if ((t & 63) == 0) wsum[t >> 6] = ls;
    __syncthreads();
    if (t == 0) atomicAdd(lacc, wsum[0] + wsum[1] + wsum[2] + wsum[3]);
}

__global__ void k_final(const double* __restrict__ lacc, float* __restrict__ loss) {
    *loss = (float)(*lacc * (1.25 / (double)OUT_ELEMS));
}

extern "C" void kernel_launch(void* const* d_in, const int* in_sizes, int n_in,
                              void* d_out, int out_size, void* d_ws, size_t ws_size,
                              hipStream_t stream) {
    const float* z  = (const float*)d_in[0];
    const float* cb = (const float*)d_in[1];
    float* out      = (float*)d_out;
    float* loss_out = out + OUT_ELEMS;
    float* idxf     = out + OUT_ELEMS + 1;

    float*  cnorm = (float*)d_ws;                                  // 64 KB
    float*  anorm = (float*)((char*)d_ws + 65536);                 // 64 KB
    int*    idxi  = (int*)((char*)d_ws + 131072);                  // 64 KB
    double* lacc  = (double*)((char*)d_ws + 196608);               // 8 B

    hipMemsetAsync(lacc, 0, sizeof(double), stream);

    k_cnorm <<<NCODES / 256, 256, 0, stream>>>(cb, cnorm);
    k_anorm <<<MTOT / 256,   256, 0, stream>>>(z, anorm);
    k_argmin<<<MTOT / BM,    256, 0, stream>>>(z, cb, cnorm, anorm, idxi, idxf);
    k_gather<<<MTOT / 64,    256, 0, stream>>>(z, cb, idxi, out, lacc);
    k_final <<<1, 1, 0, stream>>>(lacc, loss_out);
}